// Round 7
// baseline (334.081 us; speedup 1.0000x reference)
//
#include <hip/hip_runtime.h>

// ---------------------------------------------------------------------------
// SingleHeadQKV: X@{Wq,Wk,Wv} -> rope+silu -> decay-masked QK^T -> @V -> GN
// B=2, T=4096, C=1024. GEMMs: BK=64 tiles with SINGLE-BARRIER PING-PONG:
//   prologue: stage tile0 -> buf0
//   loop j:   barrier; stage tile j+1 -> buf[(j+1)&1]; MFMA from buf[j&1]
// One barrier per tile; its vmcnt drain covers loads issued a full compute
// phase earlier. Staging = linear global_load_lds(16B) from PRE-SWIZZLED
// buffers (phys 16B chunk = (col>>3)^(row&7)); frag reads XOR the chunk ->
// conflict-free b128 LDS reads with linear DMA (validated R6).
//
// ws layout (shorts):
//   Qb  [8192][1024]            @ 0        (16 MB)
//   Kb  [8192][1024]            @ 8M       (16 MB)
//   Vt  [1024][8192] transposed @ 16M      (16 MB)
//   Ab  [2*4096][4096]          @ 24M      (64 MB)   } aliased:
//   Xb  [8192][1024]            @ 24M      (16 MB)   } Xb/WT dead before
//   WT  [3072][1024]            @ 32M      ( 6 MB)   } score writes Ab
// ---------------------------------------------------------------------------

typedef __attribute__((ext_vector_type(8))) short bf16x8;
typedef __attribute__((ext_vector_type(4))) short bf16x4;
typedef __attribute__((ext_vector_type(4))) float f32x4;

#define MFMA16(a, b, c) __builtin_amdgcn_mfma_f32_16x16x32_bf16(a, b, c, 0, 0, 0)

static __device__ __forceinline__ short f2bf(float f) {
  unsigned u = __builtin_bit_cast(unsigned, f);
  u = (u + 0x7fffu + ((u >> 16) & 1u)) >> 16;
  return (short)u;
}

static __device__ __forceinline__ void gl_lds16(const void* g, void* l) {
  __builtin_amdgcn_global_load_lds(
      (const __attribute__((address_space(1))) void*)g,
      (__attribute__((address_space(3))) void*)l, 16, 0, 0);
}

// swizzled column offset for element (row, col) in a swizzled buffer
static __device__ __forceinline__ int swzc(int col, int row) {
  return (((col >> 3) ^ (row & 7)) << 3) | (col & 7);
}

#define T_LEN 4096
#define CIN 1024

// log2(0.99609375)
#define LOG2G (-0.0056465633f)
// log2(10000)/32
#define L2IF (0.41524101f)

// ---------------------------------------------------------------------------
// Kernel A+B merged: blocks [0,4096): X fp32->bf16 swizzled copy;
// blocks [4096,4864): W transpose into WT (swizzled).
// ---------------------------------------------------------------------------
__global__ __launch_bounds__(256)
void prep_kernel(const float* __restrict__ X, short* __restrict__ Xb,
                 const float* __restrict__ Wq, const float* __restrict__ Wk,
                 const float* __restrict__ Wv, short* __restrict__ WT) {
  __shared__ short tile[64][72];
  const int bx = blockIdx.x;
  const int tid = threadIdx.x;
  if (bx < 4096) {
    const int gid = bx * 256 + tid;  // 16B-chunk id
    const int row = gid >> 7;
    const int c = gid & 127;
    const float* s = &X[(size_t)gid * 8];
    float4 f0 = *(const float4*)s;
    float4 f1 = *(const float4*)(s + 4);
    bf16x8 v = {f2bf(f0.x), f2bf(f0.y), f2bf(f0.z), f2bf(f0.w),
                f2bf(f1.x), f2bf(f1.y), f2bf(f1.z), f2bf(f1.w)};
    const int pc = (c & 0x78) | ((c ^ row) & 7);
    *(bf16x8*)&Xb[(size_t)row * 1024 + pc * 8] = v;
    return;
  }
  const int bx2 = bx - 4096;  // 0..767
  const int k0 = (bx2 & 15) * 64, n0 = ((bx2 >> 4) & 15) * 64, mat = bx2 >> 8;
  const float* __restrict__ W = (mat == 0) ? Wq : (mat == 1) ? Wk : Wv;
  const int r = tid >> 4, c = tid & 15;
#pragma unroll
  for (int i = 0; i < 4; ++i) {
    int row = r + 16 * i;
    float4 f = *(const float4*)&W[(size_t)(k0 + row) * CIN + n0 + c * 4];
    tile[c * 4 + 0][row] = f2bf(f.x);
    tile[c * 4 + 1][row] = f2bf(f.y);
    tile[c * 4 + 2][row] = f2bf(f.z);
    tile[c * 4 + 3][row] = f2bf(f.w);
  }
  __syncthreads();
  const int n = tid >> 2, seg = tid & 3;
  bf16x8 lo = *(const bf16x8*)&tile[n][seg * 16];
  bf16x8 hi = *(const bf16x8*)&tile[n][seg * 16 + 8];
  const int R = mat * 1024 + n0 + n;
  const int a0 = (k0 >> 3) + seg * 2;
  short* base = &WT[(size_t)R * CIN];
  *(bf16x8*)&base[(a0 ^ (n & 7)) * 8] = lo;
  *(bf16x8*)&base[((a0 + 1) ^ (n & 7)) * 8] = hi;
}

// ---------------------------------------------------------------------------
// Shared tile-GEMM machinery.
// ---------------------------------------------------------------------------
#define GEMM_DECLS()                                   \
  const int tid = threadIdx.x;                         \
  const int lane = tid & 63, wave = tid >> 6;          \
  const int wm = wave >> 1, wn = wave & 1;             \
  const int l15 = lane & 15, quad = lane >> 4;         \
  const int srow = tid >> 3;                           \
  const int scol = (tid & 7) * 8;                      \
  const int asw = (l15 & 7);

#define ACC_INIT4(acc)                                 \
  _Pragma("unroll") for (int i = 0; i < 4; ++i)        \
  _Pragma("unroll") for (int j = 0; j < 4; ++j) {      \
    f32x4 z = {0.f, 0.f, 0.f, 0.f};                    \
    acc[i][j] = z;                                     \
  }

#define STAGE_TILE(dst, src, ld, r0, k0, nrows)        \
  _Pragma("unroll") for (int i = 0; i < (nrows) / 32; ++i) \
    gl_lds16(&src[(size_t)((r0) + i * 32 + srow) * (ld) + (k0) + scol], \
             &dst[i * 32 + srow][scol]);

#define FRAG_MFMA44(As, Bs, acc)                                            \
  {                                                                         \
    bf16x8 af[4][2], bfr[4][2];                                             \
    _Pragma("unroll") for (int im = 0; im < 4; ++im)                        \
    _Pragma("unroll") for (int ks = 0; ks < 2; ++ks)                        \
      af[im][ks] = *(const bf16x8*)&As[wm * 64 + im * 16 + l15]             \
                       [((ks * 4 + quad) ^ asw) * 8];                       \
    _Pragma("unroll") for (int in = 0; in < 4; ++in)                        \
    _Pragma("unroll") for (int ks = 0; ks < 2; ++ks)                        \
      bfr[in][ks] = *(const bf16x8*)&Bs[wn * 64 + in * 16 + l15]            \
                        [((ks * 4 + quad) ^ asw) * 8];                      \
    _Pragma("unroll") for (int ks = 0; ks < 2; ++ks)                        \
    _Pragma("unroll") for (int im = 0; im < 4; ++im)                        \
    _Pragma("unroll") for (int in = 0; in < 4; ++in)                        \
      acc[im][in] = MFMA16(af[im][ks], bfr[in][ks], acc[im][in]);           \
  }

// ---------------------------------------------------------------------------
// Kernel C: QKV GEMM, ping-pong. C[m][c] = sum_k Xb[m][k] WT[c][k].
// grid (64 m-tiles, 24 c-tiles). Epilogue: rope(Q,K cols<64, block-uniform
// guard) + silu.
// ---------------------------------------------------------------------------
__global__ __launch_bounds__(256, 2)
void qkv_gemm(const short* __restrict__ Xb, const short* __restrict__ WT,
              short* __restrict__ Qb, short* __restrict__ Kb,
              short* __restrict__ Vt) {
  __shared__ __align__(16) short As[2][128][64];
  __shared__ __align__(16) short Bs[2][128][64];
  GEMM_DECLS();
  const int m0 = blockIdx.x * 128;
  const int c0 = blockIdx.y * 128;

  f32x4 acc[4][4];
  ACC_INIT4(acc);

  STAGE_TILE(As[0], Xb, CIN, m0, 0, 128);
  STAGE_TILE(Bs[0], WT, CIN, c0, 0, 128);

#pragma unroll 1
  for (int j = 0; j < 16; ++j) {
    __syncthreads();
    if (j + 1 < 16) {
      const int kn = (j + 1) * 64;
      const int pn = (j + 1) & 1;
      STAGE_TILE(As[pn], Xb, CIN, m0, kn, 128);
      STAGE_TILE(Bs[pn], WT, CIN, c0, kn, 128);
    }
    const int p = j & 1;
    FRAG_MFMA44(As[p], Bs[p], acc);
  }

  const int mat = (c0 >> 10);  // block-uniform: 0=Q 1=K 2=V
  const bool ropeBlk = (mat < 2) && ((c0 & 1023) == 0);
#pragma unroll
  for (int im = 0; im < 4; ++im) {
#pragma unroll
    for (int in = 0; in < 4; ++in) {
      const int c = c0 + wn * 64 + in * 16 + l15;
      const int colm = c & 1023;
      const int mbase = m0 + wm * 64 + im * 16 + quad * 4;
      short vv[4];
      if (ropeBlk && colm < 64) {  // wave-uniform (colm<64 indep of lane mod)
        const float invf = exp2f(-L2IF * (float)(colm >> 1));
#pragma unroll
        for (int r = 0; r < 4; ++r) {
          float v = acc[im][in][r];
          int t = (mbase + r) & (T_LEN - 1);
          float partner = __shfl_xor(v, 1, 64);
          float ang = (float)t * invf;
          float s_, c_;
          sincosf(ang, &s_, &c_);
          v = (colm & 1) ? (v * c_ + partner * s_) : (v * c_ - partner * s_);
          v = v / (1.f + __expf(-v));
          vv[r] = f2bf(v);
        }
      } else {
#pragma unroll
        for (int r = 0; r < 4; ++r) {
          float v = acc[im][in][r];
          v = v / (1.f + __expf(-v));
          vv[r] = f2bf(v);
        }
      }
      if (mat == 0) {
#pragma unroll
        for (int r = 0; r < 4; ++r)
          Qb[(size_t)(mbase + r) * 1024 + swzc(colm, mbase + r)] = vv[r];
      } else if (mat == 1) {
#pragma unroll
        for (int r = 0; r < 4; ++r)
          Kb[(size_t)(mbase + r) * 1024 + swzc(colm, mbase + r)] = vv[r];
      } else {
        bf16x4 v4 = {vv[0], vv[1], vv[2], vv[3]};
        *(bf16x4*)&Vt[(size_t)colm * 8192 +
                      (((mbase >> 3) ^ (colm & 7)) << 3) + (mbase & 7)] = v4;
      }
    }
  }
}

// ---------------------------------------------------------------------------
// Kernel D: A' = decay o (Q K^T), bf16 swizzled, ping-pong. Triangular grid:
// 528 tiles (si>=ti) per batch, grid (528, 2).
// ---------------------------------------------------------------------------
__global__ __launch_bounds__(256, 2)
void score_kernel(const short* __restrict__ Qb, const short* __restrict__ Kb,
                  short* __restrict__ Ab) {
  int idx = blockIdx.x;
  int ti = 0;
  while (idx >= 32 - ti) { idx -= 32 - ti; ++ti; }
  const int si = ti + idx;
  const int b = blockIdx.y;
  const int s0 = si * 128, t0 = ti * 128;

  __shared__ __align__(16) short Qs[2][128][64];
  __shared__ __align__(16) short Ks[2][128][64];
  GEMM_DECLS();

  f32x4 acc[4][4];
  ACC_INIT4(acc);

  STAGE_TILE(Qs[0], Qb, 1024, b * T_LEN + t0, 0, 128);
  STAGE_TILE(Ks[0], Kb, 1024, b * T_LEN + s0, 0, 128);

#pragma unroll 1
  for (int j = 0; j < 16; ++j) {
    __syncthreads();
    if (j + 1 < 16) {
      const int kn = (j + 1) * 64;
      const int pn = (j + 1) & 1;
      STAGE_TILE(Qs[pn], Qb, 1024, b * T_LEN + t0, kn, 128);
      STAGE_TILE(Ks[pn], Kb, 1024, b * T_LEN + s0, kn, 128);
    }
    const int p = j & 1;
    FRAG_MFMA44(Qs[p], Ks[p], acc);
  }

#pragma unroll
  for (int im = 0; im < 4; ++im) {
#pragma unroll
    for (int in = 0; in < 4; ++in) {
      int s = s0 + wn * 64 + in * 16 + l15;
#pragma unroll
      for (int r = 0; r < 4; ++r) {
        int t = t0 + wm * 64 + im * 16 + quad * 4 + r;
        int d = s - t;
        float v = acc[im][in][r];
        v = (d < 0) ? 0.f : v * exp2f((float)d * LOG2G);
        Ab[((size_t)(b * T_LEN + t)) * T_LEN + swzc(s, t)] = f2bf(v);
      }
    }
  }
}

// ---------------------------------------------------------------------------
// Kernel E: out = A' V (fp32), ping-pong over a unified 65-item work list.
// Block (p,b,di) handles t-tiles p (64-row, nA=64-p items) and 63-p
// (nB=p+1 items); lookahead-1 prefetch crosses the stream boundary.
// grid (32, 2, 8) = 512 blocks, LDS 48 KB.
// ---------------------------------------------------------------------------
__global__ __launch_bounds__(256, 2)
void av_kernel(const short* __restrict__ Ab, const short* __restrict__ Vt,
               float* __restrict__ Out) {
  const int p = blockIdx.x, b = blockIdx.y, di = blockIdx.z;
  const int n0 = di * 128;
  const int t0a = p * 64, t0b = (63 - p) * 64;
  const int nA = 64 - p;  // items in stream A; stream B has p+1; total 65

  __shared__ __align__(16) short As2[2][64][64];
  __shared__ __align__(16) short Vs[2][128][64];
  GEMM_DECLS();

  f32x4 accA[2][4], accB[2][4];
#pragma unroll
  for (int i = 0; i < 2; ++i)
#pragma unroll
    for (int j = 0; j < 4; ++j) {
      f32x4 z = {0.f, 0.f, 0.f, 0.f};
      accA[i][j] = z;
      accB[i][j] = z;
    }

  // stage item 0 (always stream A: nA >= 1)
  STAGE_TILE(As2[0], Ab, T_LEN, b * T_LEN + t0a, t0a, 64);
  STAGE_TILE(Vs[0], Vt, 8192, n0, b * T_LEN + t0a, 128);

#pragma unroll 1
  for (int j = 0; j < 65; ++j) {
    __syncthreads();
    if (j + 1 < 65) {
      const int jn = j + 1;
      const int pn = jn & 1;
      const int tn = (jn < nA) ? t0a : t0b;
      const int sn = (jn < nA) ? (t0a + 64 * jn) : (t0b + 64 * (jn - nA));
      STAGE_TILE(As2[pn], Ab, T_LEN, b * T_LEN + tn, sn, 64);
      STAGE_TILE(Vs[pn], Vt, 8192, n0, b * T_LEN + sn, 128);
    }
    const int pb = j & 1;
    bf16x8 af[2][2], bfr[4][2];
#pragma unroll
    for (int im = 0; im < 2; ++im)
#pragma unroll
      for (int ks = 0; ks < 2; ++ks)
        af[im][ks] = *(const bf16x8*)&As2[pb][wm * 32 + im * 16 + l15]
                         [((ks * 4 + quad) ^ asw) * 8];
#pragma unroll
    for (int in = 0; in < 4; ++in)
#pragma unroll
      for (int ks = 0; ks < 2; ++ks)
        bfr[in][ks] = *(const bf16x8*)&Vs[pb][wn * 64 + in * 16 + l15]
                          [((ks * 4 + quad) ^ asw) * 8];
    if (j < nA) {
#pragma unroll
      for (int ks = 0; ks < 2; ++ks)
#pragma unroll
        for (int im = 0; im < 2; ++im)
#pragma unroll
          for (int in = 0; in < 4; ++in)
            accA[im][in] = MFMA16(af[im][ks], bfr[in][ks], accA[im][in]);
    } else {
#pragma unroll
      for (int ks = 0; ks < 2; ++ks)
#pragma unroll
        for (int im = 0; im < 2; ++im)
#pragma unroll
          for (int in = 0; in < 4; ++in)
            accB[im][in] = MFMA16(af[im][ks], bfr[in][ks], accB[im][in]);
    }
  }

#pragma unroll
  for (int im = 0; im < 2; ++im) {
#pragma unroll
    for (int in = 0; in < 4; ++in) {
      int n = n0 + wn * 64 + in * 16 + l15;
#pragma unroll
      for (int r = 0; r < 4; ++r) {
        int ta = t0a + wm * 32 + im * 16 + quad * 4 + r;
        int tb = t0b + wm * 32 + im * 16 + quad * 4 + r;
        Out[((size_t)(b * T_LEN + ta)) * 1024 + n] = accA[im][in][r];
        Out[((size_t)(b * T_LEN + tb)) * 1024 + n] = accB[im][in][r];
      }
    }
  }
}

// ---------------------------------------------------------------------------
// Kernel F: in-place GroupNorm (32 groups x 32 ch). one block per row.
// ---------------------------------------------------------------------------
__global__ __launch_bounds__(256)
void gn_kernel(float* __restrict__ Out, const float* __restrict__ gw,
               const float* __restrict__ gb) {
  const int row = blockIdx.x;
  const int tid = threadIdx.x;
  const int ch0 = tid * 4;
  float4 v = *(const float4*)&Out[(size_t)row * 1024 + ch0];
  float s = v.x + v.y + v.z + v.w;
  float q = v.x * v.x + v.y * v.y + v.z * v.z + v.w * v.w;
  s += __shfl_xor(s, 1, 64);
  q += __shfl_xor(q, 1, 64);
  s += __shfl_xor(s, 2, 64);
  q += __shfl_xor(q, 2, 64);
  s += __shfl_xor(s, 4, 64);
  q += __shfl_xor(q, 4, 64);
  float mean = s * (1.f / 32.f);
  float var = q * (1.f / 32.f) - mean * mean;
  float rstd = rsqrtf(var + 1e-6f);
  float4 o;
  o.x = (v.x - mean) * rstd * gw[ch0 + 0] + gb[ch0 + 0];
  o.y = (v.y - mean) * rstd * gw[ch0 + 1] + gb[ch0 + 1];
  o.z = (v.z - mean) * rstd * gw[ch0 + 2] + gb[ch0 + 2];
  o.w = (v.w - mean) * rstd * gw[ch0 + 3] + gb[ch0 + 3];
  *(float4*)&Out[(size_t)row * 1024 + ch0] = o;
}

// ---------------------------------------------------------------------------
extern "C" void kernel_launch(void* const* d_in, const int* in_sizes, int n_in,
                              void* d_out, int out_size, void* d_ws,
                              size_t ws_size, hipStream_t stream) {
  const float* X = (const float*)d_in[0];
  const float* Wq = (const float*)d_in[1];
  const float* Wk = (const float*)d_in[2];
  const float* Wv = (const float*)d_in[3];
  const float* gw = (const float*)d_in[4];
  const float* gb = (const float*)d_in[5];
  float* Out = (float*)d_out;

  short* Qb = (short*)d_ws;                        // 16 MB
  short* Kb = Qb + (size_t)8192 * 1024;            // 16 MB
  short* Vt = Kb + (size_t)8192 * 1024;            // 16 MB (transposed)
  short* Ab = Vt + (size_t)8192 * 1024;            // 64 MB
  short* Xb = Ab;                                  // aliases Ab (dead after qkv)
  short* WT = Xb + (size_t)8192 * 1024;            // 6 MB

  prep_kernel<<<4864, 256, 0, stream>>>(X, Xb, Wq, Wk, Wv, WT);
  qkv_gemm<<<dim3(64, 24), 256, 0, stream>>>(Xb, WT, Qb, Kb, Vt);
  score_kernel<<<dim3(528, 2), 256, 0, stream>>>(Qb, Kb, Ab);
  av_kernel<<<dim3(32, 2, 8), 256, 0, stream>>>(Ab, Vt, Out);
  gn_kernel<<<8192, 256, 0, stream>>>(Out, gw, gb);
}

// Round 8
// 290.167 us; speedup vs baseline: 1.1513x; 1.1513x over previous
//
#include <hip/hip_runtime.h>

// ---------------------------------------------------------------------------
// SingleHeadQKV: X@{Wq,Wk,Wv} -> rope+silu -> decay-masked QK^T -> @V -> GN
// B=2, T=4096, C=1024. GEMMs: R6 single-buffer BK=64 K-loop (proven best:
// explicit dbuf regressed via occupancy, R7). Staging = linear
// global_load_lds(16B) from PRE-SWIZZLED buffers (phys 16B chunk =
// (col>>3)^(row&7)); frag reads XOR the chunk -> conflict-free b128 LDS
// reads with linear DMA (validated R6, conflicts == 0).
// GroupNorm fused into av epilogue (in-wave shuffle reduction; each wn-wave
// owns 2 complete 32-ch groups per row). silu uses v_rcp_f32 not full div.
//
// ws layout (shorts):
//   Qb  [8192][1024]            @ 0        (16 MB)
//   Kb  [8192][1024]            @ 8M       (16 MB)
//   Vt  [1024][8192] transposed @ 16M      (16 MB)
//   Ab  [2*4096][4096]          @ 24M      (64 MB)   } aliased:
//   Xb  [8192][1024]            @ 24M      (16 MB)   } Xb/WT dead before
//   WT  [3072][1024]            @ 32M      ( 6 MB)   } score writes Ab
// ---------------------------------------------------------------------------

typedef __attribute__((ext_vector_type(8))) short bf16x8;
typedef __attribute__((ext_vector_type(4))) short bf16x4;
typedef __attribute__((ext_vector_type(4))) float f32x4;

#define MFMA16(a, b, c) __builtin_amdgcn_mfma_f32_16x16x32_bf16(a, b, c, 0, 0, 0)

static __device__ __forceinline__ short f2bf(float f) {
  unsigned u = __builtin_bit_cast(unsigned, f);
  u = (u + 0x7fffu + ((u >> 16) & 1u)) >> 16;
  return (short)u;
}

static __device__ __forceinline__ float fast_silu(float v) {
  // v / (1+e^-v) with v_rcp_f32 (~1 ulp) instead of the 10-instr exact div
  return v * __builtin_amdgcn_rcpf(1.f + __expf(-v));
}

static __device__ __forceinline__ void gl_lds16(const void* g, void* l) {
  __builtin_amdgcn_global_load_lds(
      (const __attribute__((address_space(1))) void*)g,
      (__attribute__((address_space(3))) void*)l, 16, 0, 0);
}

// swizzled column offset for element (row, col) in a swizzled buffer
static __device__ __forceinline__ int swzc(int col, int row) {
  return (((col >> 3) ^ (row & 7)) << 3) | (col & 7);
}

#define T_LEN 4096
#define CIN 1024

// log2(0.99609375)
#define LOG2G (-0.0056465633f)
// log2(10000)/32
#define L2IF (0.41524101f)

// ---------------------------------------------------------------------------
// Kernel A+B merged: blocks [0,4096): X fp32->bf16 swizzled copy;
// blocks [4096,4864): W transpose into WT (swizzled).
// ---------------------------------------------------------------------------
__global__ __launch_bounds__(256)
void prep_kernel(const float* __restrict__ X, short* __restrict__ Xb,
                 const float* __restrict__ Wq, const float* __restrict__ Wk,
                 const float* __restrict__ Wv, short* __restrict__ WT) {
  __shared__ short tile[64][72];
  const int bx = blockIdx.x;
  const int tid = threadIdx.x;
  if (bx < 4096) {
    const int gid = bx * 256 + tid;  // 16B-chunk id
    const int row = gid >> 7;
    const int c = gid & 127;
    const float* s = &X[(size_t)gid * 8];
    float4 f0 = *(const float4*)s;
    float4 f1 = *(const float4*)(s + 4);
    bf16x8 v = {f2bf(f0.x), f2bf(f0.y), f2bf(f0.z), f2bf(f0.w),
                f2bf(f1.x), f2bf(f1.y), f2bf(f1.z), f2bf(f1.w)};
    const int pc = (c & 0x78) | ((c ^ row) & 7);
    *(bf16x8*)&Xb[(size_t)row * 1024 + pc * 8] = v;
    return;
  }
  const int bx2 = bx - 4096;  // 0..767
  const int k0 = (bx2 & 15) * 64, n0 = ((bx2 >> 4) & 15) * 64, mat = bx2 >> 8;
  const float* __restrict__ W = (mat == 0) ? Wq : (mat == 1) ? Wk : Wv;
  const int r = tid >> 4, c = tid & 15;
#pragma unroll
  for (int i = 0; i < 4; ++i) {
    int row = r + 16 * i;
    float4 f = *(const float4*)&W[(size_t)(k0 + row) * CIN + n0 + c * 4];
    tile[c * 4 + 0][row] = f2bf(f.x);
    tile[c * 4 + 1][row] = f2bf(f.y);
    tile[c * 4 + 2][row] = f2bf(f.z);
    tile[c * 4 + 3][row] = f2bf(f.w);
  }
  __syncthreads();
  const int n = tid >> 2, seg = tid & 3;
  bf16x8 lo = *(const bf16x8*)&tile[n][seg * 16];
  bf16x8 hi = *(const bf16x8*)&tile[n][seg * 16 + 8];
  const int R = mat * 1024 + n0 + n;
  const int a0 = (k0 >> 3) + seg * 2;
  short* base = &WT[(size_t)R * CIN];
  *(bf16x8*)&base[(a0 ^ (n & 7)) * 8] = lo;
  *(bf16x8*)&base[((a0 + 1) ^ (n & 7)) * 8] = hi;
}

// ---------------------------------------------------------------------------
// Shared tile-GEMM machinery (R6 single-buffer).
// ---------------------------------------------------------------------------
#define GEMM_DECLS()                                   \
  const int tid = threadIdx.x;                         \
  const int lane = tid & 63, wave = tid >> 6;          \
  const int wm = wave >> 1, wn = wave & 1;             \
  const int l15 = lane & 15, quad = lane >> 4;         \
  const int srow = tid >> 3;                           \
  const int scol = (tid & 7) * 8;                      \
  const int asw = (l15 & 7);

#define ACC_INIT4(acc)                                 \
  _Pragma("unroll") for (int i = 0; i < 4; ++i)        \
  _Pragma("unroll") for (int j = 0; j < 4; ++j) {      \
    f32x4 z = {0.f, 0.f, 0.f, 0.f};                    \
    acc[i][j] = z;                                     \
  }

#define STAGE_TILE(dst, src, ld, r0, k0, nrows)        \
  _Pragma("unroll") for (int i = 0; i < (nrows) / 32; ++i) \
    gl_lds16(&src[(size_t)((r0) + i * 32 + srow) * (ld) + (k0) + scol], \
             &dst[i * 32 + srow][scol]);

#define FRAG_MFMA44(As, Bs, acc)                                            \
  {                                                                         \
    bf16x8 af[4][2], bfr[4][2];                                             \
    _Pragma("unroll") for (int im = 0; im < 4; ++im)                        \
    _Pragma("unroll") for (int ks = 0; ks < 2; ++ks)                        \
      af[im][ks] = *(const bf16x8*)&As[wm * 64 + im * 16 + l15]             \
                       [((ks * 4 + quad) ^ asw) * 8];                       \
    _Pragma("unroll") for (int in = 0; in < 4; ++in)                        \
    _Pragma("unroll") for (int ks = 0; ks < 2; ++ks)                        \
      bfr[in][ks] = *(const bf16x8*)&Bs[wn * 64 + in * 16 + l15]            \
                        [((ks * 4 + quad) ^ asw) * 8];                      \
    _Pragma("unroll") for (int ks = 0; ks < 2; ++ks)                        \
    _Pragma("unroll") for (int im = 0; im < 4; ++im)                        \
    _Pragma("unroll") for (int in = 0; in < 4; ++in)                        \
      acc[im][in] = MFMA16(af[im][ks], bfr[in][ks], acc[im][in]);           \
  }

// ---------------------------------------------------------------------------
// Kernel C: QKV GEMM. C[m][c] = sum_k Xb[m][k] WT[c][k].  M=8192, N=3072.
// grid (64 m-tiles, 24 c-tiles). Epilogue: rope(Q,K cols<64, block-uniform
// guard) + fast silu.
// ---------------------------------------------------------------------------
__global__ __launch_bounds__(256, 2)
void qkv_gemm(const short* __restrict__ Xb, const short* __restrict__ WT,
              short* __restrict__ Qb, short* __restrict__ Kb,
              short* __restrict__ Vt) {
  __shared__ __align__(16) short As[128][64];
  __shared__ __align__(16) short Bs[128][64];
  GEMM_DECLS();
  const int m0 = blockIdx.x * 128;
  const int c0 = blockIdx.y * 128;

  f32x4 acc[4][4];
  ACC_INIT4(acc);

  for (int k0 = 0; k0 < CIN; k0 += 64) {
    __syncthreads();
    STAGE_TILE(As, Xb, CIN, m0, k0, 128);
    STAGE_TILE(Bs, WT, CIN, c0, k0, 128);
    __syncthreads();
    FRAG_MFMA44(As, Bs, acc);
  }

  const int mat = (c0 >> 10);  // block-uniform: 0=Q 1=K 2=V
  const bool ropeBlk = (mat < 2) && ((c0 & 1023) == 0);
#pragma unroll
  for (int im = 0; im < 4; ++im) {
#pragma unroll
    for (int in = 0; in < 4; ++in) {
      const int c = c0 + wn * 64 + in * 16 + l15;
      const int colm = c & 1023;
      const int mbase = m0 + wm * 64 + im * 16 + quad * 4;
      short vv[4];
      if (ropeBlk && colm < 64) {  // wave-uniform (colm<64 indep of lane)
        const float invf = exp2f(-L2IF * (float)(colm >> 1));
#pragma unroll
        for (int r = 0; r < 4; ++r) {
          float v = acc[im][in][r];
          int t = (mbase + r) & (T_LEN - 1);
          float partner = __shfl_xor(v, 1, 64);
          float ang = (float)t * invf;
          float s_ = __sinf(ang), c_ = __cosf(ang);
          v = (colm & 1) ? (v * c_ + partner * s_) : (v * c_ - partner * s_);
          vv[r] = f2bf(fast_silu(v));
        }
      } else {
#pragma unroll
        for (int r = 0; r < 4; ++r) vv[r] = f2bf(fast_silu(acc[im][in][r]));
      }
      if (mat == 0) {
#pragma unroll
        for (int r = 0; r < 4; ++r)
          Qb[(size_t)(mbase + r) * 1024 + swzc(colm, mbase + r)] = vv[r];
      } else if (mat == 1) {
#pragma unroll
        for (int r = 0; r < 4; ++r)
          Kb[(size_t)(mbase + r) * 1024 + swzc(colm, mbase + r)] = vv[r];
      } else {
        bf16x4 v4 = {vv[0], vv[1], vv[2], vv[3]};
        *(bf16x4*)&Vt[(size_t)colm * 8192 +
                      (((mbase >> 3) ^ (colm & 7)) << 3) + (mbase & 7)] = v4;
      }
    }
  }
}

// ---------------------------------------------------------------------------
// Kernel D: A' = decay o (Q K^T), bf16 swizzled. Triangular grid: 528 tiles
// (si>=ti) per batch, grid (528, 2). Uniform work per block.
// ---------------------------------------------------------------------------
__global__ __launch_bounds__(256, 2)
void score_kernel(const short* __restrict__ Qb, const short* __restrict__ Kb,
                  short* __restrict__ Ab) {
  int idx = blockIdx.x;
  int ti = 0;
  while (idx >= 32 - ti) { idx -= 32 - ti; ++ti; }
  const int si = ti + idx;
  const int b = blockIdx.y;
  const int s0 = si * 128, t0 = ti * 128;

  __shared__ __align__(16) short Qs[128][64];
  __shared__ __align__(16) short Ks[128][64];
  GEMM_DECLS();

  f32x4 acc[4][4];
  ACC_INIT4(acc);

  for (int k0 = 0; k0 < 1024; k0 += 64) {
    __syncthreads();
    STAGE_TILE(Qs, Qb, 1024, b * T_LEN + t0, k0, 128);
    STAGE_TILE(Ks, Kb, 1024, b * T_LEN + s0, k0, 128);
    __syncthreads();
    FRAG_MFMA44(Qs, Ks, acc);
  }

#pragma unroll
  for (int im = 0; im < 4; ++im) {
#pragma unroll
    for (int in = 0; in < 4; ++in) {
      int s = s0 + wn * 64 + in * 16 + l15;
#pragma unroll
      for (int r = 0; r < 4; ++r) {
        int t = t0 + wm * 64 + im * 16 + quad * 4 + r;
        int d = s - t;
        float v = acc[im][in][r];
        v = (d < 0) ? 0.f : v * exp2f((float)d * LOG2G);
        Ab[((size_t)(b * T_LEN + t)) * T_LEN + swzc(s, t)] = f2bf(v);
      }
    }
  }
}

// ---------------------------------------------------------------------------
// Kernel E: out = GroupNorm(A' V) (fp32). 64-row t-tiles, balanced pairing
// (p, 63-p): uniform 65 BK64-iters per block. grid (32, 2, 8) = 512 blocks.
// di slowest: A-stream-sharing blocks land on one XCD.
// GN fused: each wn-wave holds 2 complete 32-ch groups per row (in-pair x
// 16 l15 lanes) -> shfl_xor(1,2,4,8) reduction, no LDS, no extra pass.
// ---------------------------------------------------------------------------
__global__ __launch_bounds__(256, 2)
void av_kernel(const short* __restrict__ Ab, const short* __restrict__ Vt,
               const float* __restrict__ gw, const float* __restrict__ gb,
               float* __restrict__ Out) {
  const int p = blockIdx.x, b = blockIdx.y, di = blockIdx.z;
  const int n0 = di * 128;

  __shared__ __align__(16) short As2[64][64];
  __shared__ __align__(16) short Vs[128][64];
  GEMM_DECLS();

  // gamma/beta for this thread's 4 channel positions (in = 0..3)
  float w4[4], b4[4];
#pragma unroll
  for (int in = 0; in < 4; ++in) {
    int n = n0 + wn * 64 + in * 16 + l15;
    w4[in] = gw[n];
    b4[in] = gb[n];
  }

#pragma unroll 1
  for (int half = 0; half < 2; ++half) {
    const int ti2 = half ? (63 - p) : p;  // 64-row tile index
    const int t0 = ti2 * 64;

    f32x4 acc[2][4];
#pragma unroll
    for (int i = 0; i < 2; ++i)
#pragma unroll
      for (int j = 0; j < 4; ++j) {
        f32x4 z = {0.f, 0.f, 0.f, 0.f};
        acc[i][j] = z;
      }

    for (int s = t0; s < T_LEN; s += 64) {
      __syncthreads();
      STAGE_TILE(As2, Ab, T_LEN, b * T_LEN + t0, s, 64);
      STAGE_TILE(Vs, Vt, 8192, n0, b * T_LEN + s, 128);
      __syncthreads();
      bf16x8 af[2][2], bfr[4][2];
#pragma unroll
      for (int im = 0; im < 2; ++im)
#pragma unroll
        for (int ks = 0; ks < 2; ++ks)
          af[im][ks] = *(const bf16x8*)&As2[wm * 32 + im * 16 + l15]
                           [((ks * 4 + quad) ^ asw) * 8];
#pragma unroll
      for (int in = 0; in < 4; ++in)
#pragma unroll
        for (int ks = 0; ks < 2; ++ks)
          bfr[in][ks] = *(const bf16x8*)&Vs[wn * 64 + in * 16 + l15]
                            [((ks * 4 + quad) ^ asw) * 8];
#pragma unroll
      for (int ks = 0; ks < 2; ++ks)
#pragma unroll
        for (int im = 0; im < 2; ++im)
#pragma unroll
          for (int in = 0; in < 4; ++in)
            acc[im][in] = MFMA16(af[im][ks], bfr[in][ks], acc[im][in]);
    }

    // fused GroupNorm + store. Group g (32 ch) = in-pair {2g, 2g+1} x l15.
#pragma unroll
    for (int im = 0; im < 2; ++im) {
#pragma unroll
      for (int r = 0; r < 4; ++r) {
        int t = t0 + wm * 32 + im * 16 + quad * 4 + r;
        float* orow = &Out[((size_t)(b * T_LEN + t)) * 1024];
#pragma unroll
        for (int g = 0; g < 2; ++g) {
          float a0 = acc[im][g * 2][r], a1 = acc[im][g * 2 + 1][r];
          float s = a0 + a1;
          float q = a0 * a0 + a1 * a1;
          s += __shfl_xor(s, 1, 64);
          q += __shfl_xor(q, 1, 64);
          s += __shfl_xor(s, 2, 64);
          q += __shfl_xor(q, 2, 64);
          s += __shfl_xor(s, 4, 64);
          q += __shfl_xor(q, 4, 64);
          s += __shfl_xor(s, 8, 64);
          q += __shfl_xor(q, 8, 64);
          float mean = s * (1.f / 32.f);
          float var = q * (1.f / 32.f) - mean * mean;
          float rstd = rsqrtf(var + 1e-6f);
          int n = n0 + wn * 64 + g * 32 + l15;
          orow[n] = (a0 - mean) * rstd * w4[g * 2] + b4[g * 2];
          orow[n + 16] = (a1 - mean) * rstd * w4[g * 2 + 1] + b4[g * 2 + 1];
        }
      }
    }
  }
}

// ---------------------------------------------------------------------------
extern "C" void kernel_launch(void* const* d_in, const int* in_sizes, int n_in,
                              void* d_out, int out_size, void* d_ws,
                              size_t ws_size, hipStream_t stream) {
  const float* X = (const float*)d_in[0];
  const float* Wq = (const float*)d_in[1];
  const float* Wk = (const float*)d_in[2];
  const float* Wv = (const float*)d_in[3];
  const float* gw = (const float*)d_in[4];
  const float* gb = (const float*)d_in[5];
  float* Out = (float*)d_out;

  short* Qb = (short*)d_ws;                        // 16 MB
  short* Kb = Qb + (size_t)8192 * 1024;            // 16 MB
  short* Vt = Kb + (size_t)8192 * 1024;            // 16 MB (transposed)
  short* Ab = Vt + (size_t)8192 * 1024;            // 64 MB
  short* Xb = Ab;                                  // aliases Ab (dead after qkv)
  short* WT = Xb + (size_t)8192 * 1024;            // 6 MB

  prep_kernel<<<4864, 256, 0, stream>>>(X, Xb, Wq, Wk, Wv, WT);
  qkv_gemm<<<dim3(64, 24), 256, 0, stream>>>(Xb, WT, Qb, Kb, Vt);
  score_kernel<<<dim3(528, 2), 256, 0, stream>>>(Qb, Kb, Ab);
  av_kernel<<<dim3(32, 2, 8), 256, 0, stream>>>(Ab, Vt, gw, gb, Out);
}